// Round 13
// baseline (396.340 us; speedup 1.0000x reference)
//
#include <hip/hip_runtime.h>
#include <hip/hip_bf16.h>

#define NN 768
#define NE 24576
#define NPOS 4096
#define NCELL (NN*NN)   // 589824
#define NBLK 2304
#define NBIG 4608       // k_big: 64-thread blocks, 128 cells/block, 2 cells/thread
#define NREP 64

typedef __hip_bfloat16 bf16;

__device__ __forceinline__ float ldf(const void* p, int i, int mode) {
    return mode ? __bfloat162float(((const bf16*)p)[i]) : ((const float*)p)[i];
}
__device__ __forceinline__ float aread(float* p) { return atomicAdd(p, 0.f); }
__device__ __forceinline__ int areadi(int* p) { return atomicAdd(p, 0); }

template<int D, int HALF>
__device__ __forceinline__ void redRound(float* v, int lane) {
#pragma unroll
    for (int i = 0; i < HALF; i++) {
        float snd = (lane & D) ? v[i] : v[i + HALF];
        float r = __shfl_xor(snd, D);
        v[i] = ((lane & D) ? v[i + HALF] : v[i]) + r;
    }
}

#define DOT4(Z, A, W) Z += A.x * W.x + A.y * W.y + A.z * W.z + A.w * W.w

// ---------------- conv (block 0) + aux clear (block 1) ----------------
__global__ void k_conv(const void* __restrict__ gW, const void* __restrict__ gB,
                       const void* __restrict__ m1W, const void* __restrict__ m1B,
                       const void* __restrict__ m2W, const void* __restrict__ m2B,
                       const void* __restrict__ m3W, const void* __restrict__ m3B,
                       const void* __restrict__ lW,  const void* __restrict__ lB,
                       const void* __restrict__ emb,
                       float* __restrict__ stats, int* __restrict__ cursor,
                       int* __restrict__ rowlen, int* __restrict__ rtot, int* __restrict__ dcs,
                       int* __restrict__ modeg,
                       float* __restrict__ gwf, float* __restrict__ gbf,
                       float* __restrict__ w1f, float* __restrict__ b1f,
                       float* __restrict__ w2f, float* __restrict__ b2f,
                       float* __restrict__ w3q, float* __restrict__ linf, float* __restrict__ linb) {
    int t = threadIdx.x;
    if (blockIdx.x == 1) {
        for (int i = t; i < NN; i += 256) { cursor[i] = 0; rowlen[i] = 0; rtot[i] = 0; }
        for (int i = t; i < NREP * 80; i += 256) stats[i] = 0.f;
        if (t < 8) dcs[t] = 0;
        return;
    }
    __shared__ int bad;
    if (t == 0) bad = 0;
    __syncthreads();
    int local = 0;
    for (int i = t; i < 3232; i += 256) {
        float a = fabsf(__bfloat162float(((const bf16*)emb)[i]));
        if (!(a < 100.f)) local = 1;
    }
    if (local) atomicOr(&bad, 1);
    __syncthreads();
    int mode = bad ? 0 : 1;
    if (t == 0) *modeg = mode;
    for (int i = t; i < 2048; i += 256) {
        gwf[i] = ldf(gW, i, mode);
        w1f[i] = ldf(m1W, i, mode);
        w2f[i] = ldf(m2W, i, mode);
    }
    for (int i = t; i < 64; i += 256) { gbf[i] = ldf(gB, i, mode); linf[i] = ldf(lW, i, mode); }
    if (t < 32) { b1f[t] = ldf(m1B, t, mode); b2f[t] = ldf(m2B, t, mode); }
    // w3q row d (stride 36 floats, 16B-aligned): [W3[0..31][d], ind, b3, 0, 0]
    for (int i = t; i < 1056; i += 256) { int c = i >> 5, d = i & 31; w3q[d * 36 + c] = ldf(m3W, i, mode); }
    if (t < 32) { w3q[t * 36 + 33] = ldf(m3B, t, mode); w3q[t * 36 + 34] = 0.f; w3q[t * 36 + 35] = 0.f; }
    if (t == 0) linb[0] = ldf(lB, 0, mode);
}

// ---------------- edge scatter; last block: row scan + dinv ----------------
__global__ void k_scatter(const int* __restrict__ ei, int* __restrict__ cell, int* __restrict__ rowlen,
                          int* __restrict__ row_ptr, float* __restrict__ dinv, int* __restrict__ dc) {
    __shared__ int amlast;
    __shared__ int sI[256];
    int t = threadIdx.x;
    int e = blockIdx.x * 256 + t;
    int a = ei[e], b = ei[NE + e];
    if ((unsigned)a < (unsigned)NN && (unsigned)b < (unsigned)NN) {
        int old = atomicAdd(&cell[a * NN + b], 1);
        if (old == 0) atomicAdd(&rowlen[a], 1);
    }
    __syncthreads();
    if (t == 0) { __threadfence(); amlast = (atomicAdd(dc, 1) == 95) ? 1 : 0; }
    __syncthreads();
    if (!amlast) return;
    int i0 = 3 * t;
    int r0 = areadi(&rowlen[i0]), r1 = areadi(&rowlen[i0 + 1]), r2 = areadi(&rowlen[i0 + 2]);
    dinv[i0]     = rsqrtf((float)r0 + 1.f);
    dinv[i0 + 1] = rsqrtf((float)r1 + 1.f);
    dinv[i0 + 2] = rsqrtf((float)r2 + 1.f);
    int s3 = r0 + r1 + r2;
    sI[t] = s3;
    __syncthreads();
    for (int off = 1; off < 256; off <<= 1) {
        int tmp = (t >= off) ? sI[t - off] : 0;
        __syncthreads();
        sI[t] += tmp;
        __syncthreads();
    }
    int excl = sI[t] - s3;
    row_ptr[i0] = excl;
    row_ptr[i0 + 1] = excl + r0;
    row_ptr[i0 + 2] = excl + r0 + r1;
    if (t == 255) row_ptr[NN] = sI[255];
}

// ---------------- CSR fill + rtot (b<2304) || emb gather E -> bufA (b>=2304) ----------------
__global__ void k_fill(int* __restrict__ cell, const int* __restrict__ row_ptr, int* __restrict__ cursor,
                       int* __restrict__ col_idx, float* __restrict__ cntv, int* __restrict__ pr_row,
                       const int* __restrict__ rowlen, int* __restrict__ rtot,
                       const int* __restrict__ x, const void* __restrict__ emb,
                       const int* __restrict__ modep, float* __restrict__ bufA) {
    int t = threadIdx.x;
    int b = blockIdx.x;
    if (b < NBLK) {
        int idx = b * 256 + t;
        int i = idx / NN;
        int j = idx - i * NN;
        int cv = cell[idx];
        if (cv > 0) {
            int p = row_ptr[i] + atomicAdd(&cursor[i], 1);
            col_idx[p] = j; cntv[p] = (float)cv; pr_row[p] = i;
            cell[idx] = p;
            atomicAdd(&rtot[i], rowlen[j]);
        } else cell[idx] = -1;
    } else {
        int idx = (b - NBLK) * 256 + t;   // 768*32
        int i = idx >> 5, k = idx & 31;
        int xi = x[i]; if (xi < 0) xi = 0; if (xi > 100) xi = 100;
        bufA[idx] = ldf(emb, xi * 32 + k, *modep);
    }
}

// ---------------- b==0: row_base scan || b>=1: agg(E in bufA) then @W0 -> bufB ----------------
__global__ void k_aggmw0(const int* __restrict__ rtot, int* __restrict__ row_base,
                         const int* __restrict__ row_ptr, const int* __restrict__ col_idx,
                         const float* __restrict__ bufA, const float* __restrict__ dinv,
                         const float* __restrict__ gwf, const float* __restrict__ gbf,
                         float* __restrict__ bufB) {
    int t = threadIdx.x;
    if (blockIdx.x == 0) {
        __shared__ int sI[256];
        int r3[3]; int s3 = 0;
#pragma unroll
        for (int q = 0; q < 3; q++) { r3[q] = rtot[3 * t + q]; s3 += r3[q]; }
        sI[t] = s3;
        __syncthreads();
        for (int off = 1; off < 256; off <<= 1) {
            int tmp = (t >= off) ? sI[t - off] : 0;
            __syncthreads();
            sI[t] += tmp;
            __syncthreads();
        }
        int run = sI[t] - s3;
        row_base[3 * t] = run;
        row_base[3 * t + 1] = run + r3[0];
        row_base[3 * t + 2] = run + r3[0] + r3[1];
        return;
    }
    __shared__ float sg[8][32];
    int li = t >> 5, k = t & 31;
    int i = (blockIdx.x - 1) * 8 + li;
    int base = row_ptr[i], len = row_ptr[i + 1] - base;
    float di = dinv[i];
    float acc = di * bufA[i * 32 + k];
    for (int e = 0; e < len; e++) {
        int c = col_idx[base + e];
        acc += dinv[c] * bufA[c * 32 + k];
    }
    sg[li][k] = di * acc;     // aggregated in E-space
    __syncthreads();
    int d = k;
    float s = gbf[d];
#pragma unroll
    for (int kk = 0; kk < 32; kk++) s += sg[li][kk] * gwf[kk * 32 + d];
    bufB[i * 32 + d] = s;
}

// ---------------- per-row path histogram (b<768) || nrm0 from bufB (b==768) ----------------
__global__ void k_hist(const int* __restrict__ row_ptr, const int* __restrict__ col_idx,
                       const int* __restrict__ row_base,
                       int* __restrict__ pcur, int2* __restrict__ paths2, int cap,
                       const float* __restrict__ bufB, float* __restrict__ nrm0) {
    int t = threadIdx.x;
    if (blockIdx.x == NN) {
        __shared__ float r1[256], r2[256];
        int dd = t & 31, g = t >> 5;
        float s = 0.f, s2 = 0.f;
        for (int r = g; r < NN; r += 8) { float v = bufB[r * 32 + dd]; s += v; s2 += v * v; }
        r1[t] = s; r2[t] = s2;
        __syncthreads();
        if (t < 32) {
            float a = 0.f, b2 = 0.f;
            for (int k = 0; k < 8; k++) { a += r1[k * 32 + t]; b2 += r2[k * 32 + t]; }
            float mean = a / (float)NN;
            float var = b2 / (float)NN - mean * mean;
            nrm0[t] = mean;
            nrm0[32 + t] = rsqrtf(fmaxf(var, 0.f) + 1e-5f);
        }
        return;
    }
    __shared__ int hist[NN];
    __shared__ int sc[256];
    int i = blockIdx.x;
    int base = row_ptr[i], len = row_ptr[i + 1] - base;
    int rb = row_base[i];
    int wave = t >> 6, lane = t & 63;
    for (int j = t; j < NN; j += 256) hist[j] = 0;
    __syncthreads();
    for (int ee = wave; ee < len; ee += 4) {
        int k = col_idx[base + ee];
        int kb = row_ptr[k], ke = row_ptr[k + 1];
        for (int e = kb + lane; e < ke; e += 64) atomicAdd(&hist[col_idx[e]], 1);
    }
    __syncthreads();
    int h0 = hist[3 * t], h1 = hist[3 * t + 1], h2 = hist[3 * t + 2];
    int s3 = h0 + h1 + h2;
    sc[t] = s3;
    __syncthreads();
    for (int off = 1; off < 256; off <<= 1) {
        int tmp = (t >= off) ? sc[t - off] : 0;
        __syncthreads();
        sc[t] += tmp;
        __syncthreads();
    }
    int excl = sc[t] - s3;
    int n0 = i * NN + 3 * t;
    pcur[n0]     = rb + excl + h0;            // absolute END offsets
    pcur[n0 + 1] = rb + excl + h0 + h1;
    pcur[n0 + 2] = rb + excl + h0 + h1 + h2;
    hist[3 * t] = excl;
    hist[3 * t + 1] = excl + h0;
    hist[3 * t + 2] = excl + h0 + h1;
    __syncthreads();
    for (int ee = wave; ee < len; ee += 4) {
        int e1 = base + ee;
        int k = col_idx[e1];
        int kb = row_ptr[k], ke = row_ptr[k + 1];
        for (int e = kb + lane; e < ke; e += 64) {
            int j = col_idx[e];
            int slot = rb + atomicAdd(&hist[j], 1);
            if (slot < cap) paths2[slot] = make_int2(e1, e);
        }
    }
}

// ---------------- agg(g(bufB,nrm0)) then @W1 -> bufA ----------------
__global__ void k_aggmw1(const int* __restrict__ row_ptr, const int* __restrict__ col_idx,
                         const float* __restrict__ bufB, const float* __restrict__ nrm0,
                         const float* __restrict__ dinv,
                         const float* __restrict__ gwf, const float* __restrict__ gbf,
                         float* __restrict__ bufA) {
    __shared__ float sg[8][32];
    int t = threadIdx.x;
    int li = t >> 5, k = t & 31;
    int i = blockIdx.x * 8 + li;
    float mk = nrm0[k], rk = nrm0[32 + k];
    int base = row_ptr[i], len = row_ptr[i + 1] - base;
    float di = dinv[i];
    float acc = di * fmaxf((bufB[i * 32 + k] - mk) * rk, 0.f);
    for (int e = 0; e < len; e++) {
        int c = col_idx[base + e];
        acc += dinv[c] * fmaxf((bufB[c * 32 + k] - mk) * rk, 0.f);
    }
    sg[li][k] = di * acc;
    __syncthreads();
    int d = k;
    const float* W = gwf + 1024;
    float s = gbf[32 + d];
#pragma unroll
    for (int kk = 0; kk < 32; kk++) s += sg[li][kk] * W[kk * 32 + d];
    bufA[i * 32 + d] = s;
}

// ---------------- column stats of bufA -> nrm1 ----------------
__global__ void k_st1(const float* __restrict__ bufA, float* __restrict__ nrm1) {
    __shared__ float r1[256], r2[256];
    int t = threadIdx.x;
    int dd = t & 31, g = t >> 5;
    float s = 0.f, s2 = 0.f;
    for (int r = g; r < NN; r += 8) { float v = bufA[r * 32 + dd]; s += v; s2 += v * v; }
    r1[t] = s; r2[t] = s2;
    __syncthreads();
    if (t < 32) {
        float a = 0.f, b2 = 0.f;
        for (int k = 0; k < 8; k++) { a += r1[k * 32 + t]; b2 += r2[k * 32 + t]; }
        float mean = a / (float)NN;
        float var = b2 / (float)NN - mean * mean;
        nrm1[t] = mean;
        nrm1[32 + t] = rsqrtf(fmaxf(var, 0.f) + 1e-5f);
    }
}

// ---------------- edge MLP w/ inline norm1 (b<3072) || h write (b>=3072) ----------------
__global__ void k_emlp(const float* __restrict__ bufA, const float* __restrict__ nrm1,
                       const int* __restrict__ row_ptr, const int* __restrict__ col_idx,
                       const int* __restrict__ pr_row, const float* __restrict__ cntv,
                       const float* __restrict__ w1f, const float* __restrict__ b1f,
                       const float* __restrict__ w2f, const float* __restrict__ b2f,
                       float* __restrict__ xep, float* __restrict__ mulp, float* __restrict__ h) {
    int t = threadIdx.x;
    int b = blockIdx.x;
    if (b < 3072) {
        int d = t & 31;
        int p = b * 8 + (t >> 5);
        if (p >= row_ptr[NN]) {
            if (p < NE) { xep[p * 32 + d] = 0.f; mulp[p * 32 + d] = 0.f; }
            return;
        }
        int i = pr_row[p], j = col_idx[p];
        float a1 = b1f[d], a2 = b2f[d];
#pragma unroll
        for (int c = 0; c < 32; c++) {
            float hv = fmaxf((bufA[i * 32 + c] - nrm1[c]) * nrm1[32 + c], 0.f);
            a1 += hv * w1f[c * 32 + d];
            a2 += hv * w2f[c * 32 + d];
        }
#pragma unroll
        for (int c = 0; c < 32; c++) {
            float hv = fmaxf((bufA[j * 32 + c] - nrm1[c]) * nrm1[32 + c], 0.f);
            a1 += hv * w1f[(32 + c) * 32 + d];
            a2 += hv * w2f[(32 + c) * 32 + d];
        }
        float cv = cntv[p];
        xep[p * 32 + d]  = cv * fmaxf(a1, 0.f);
        mulp[p * 32 + d] = cv * fmaxf(a2, 0.f);
    } else {
        int idx = (b - 3072) * 256 + t;
        int d = idx & 31;
        h[idx] = fmaxf((bufA[idx] - nrm1[d]) * nrm1[32 + d], 0.f);
    }
}

// ---------------- big: single-wave blocks, 2 cells/thread, wave-level stats ----------------
__global__ __launch_bounds__(64, 4) void k_big(const int* __restrict__ pcur,
                                               const int2* __restrict__ paths2,
                                               const int* __restrict__ cell,
                                               const float4* __restrict__ xep4, const float4* __restrict__ mulp4,
                                               const float* __restrict__ w3q,
                                               float* __restrict__ stats, int* __restrict__ done,
                                               float* __restrict__ nrm, int cap) {
    int t = threadIdx.x;            // == lane (single-wave block)
    int b = blockIdx.x;
    int n0 = b * 128 + 2 * t;
    int p0a = (n0 == 0) ? 0 : pcur[n0 - 1];
    int p1a = pcur[n0];
    int p1b = pcur[n0 + 1];
    if (p0a > cap) p0a = cap; if (p1a > cap) p1a = cap; if (p1b > cap) p1b = cap;
    float4 a0 = {0.f,0.f,0.f,0.f}, a1 = a0, a2 = a0, a3 = a0, a4 = a0, a5 = a0, a6 = a0, a7 = a0;
    float4 c0 = a0, c1 = a0, c2 = a0, c3 = a0, c4 = a0, c5 = a0, c6 = a0, c7 = a0;
    for (int p = p0a; p < p1a; p++) {
        int2 rec = paths2[p];
        const float4* xr = xep4 + rec.x * 8;
        const float4* mr = mulp4 + rec.y * 8;
        float4 xv, mv;
        xv = xr[0]; mv = mr[0]; a0.x += xv.x*mv.x; a0.y += xv.y*mv.y; a0.z += xv.z*mv.z; a0.w += xv.w*mv.w;
        xv = xr[1]; mv = mr[1]; a1.x += xv.x*mv.x; a1.y += xv.y*mv.y; a1.z += xv.z*mv.z; a1.w += xv.w*mv.w;
        xv = xr[2]; mv = mr[2]; a2.x += xv.x*mv.x; a2.y += xv.y*mv.y; a2.z += xv.z*mv.z; a2.w += xv.w*mv.w;
        xv = xr[3]; mv = mr[3]; a3.x += xv.x*mv.x; a3.y += xv.y*mv.y; a3.z += xv.z*mv.z; a3.w += xv.w*mv.w;
        xv = xr[4]; mv = mr[4]; a4.x += xv.x*mv.x; a4.y += xv.y*mv.y; a4.z += xv.z*mv.z; a4.w += xv.w*mv.w;
        xv = xr[5]; mv = mr[5]; a5.x += xv.x*mv.x; a5.y += xv.y*mv.y; a5.z += xv.z*mv.z; a5.w += xv.w*mv.w;
        xv = xr[6]; mv = mr[6]; a6.x += xv.x*mv.x; a6.y += xv.y*mv.y; a6.z += xv.z*mv.z; a6.w += xv.w*mv.w;
        xv = xr[7]; mv = mr[7]; a7.x += xv.x*mv.x; a7.y += xv.y*mv.y; a7.z += xv.z*mv.z; a7.w += xv.w*mv.w;
    }
    for (int p = p1a; p < p1b; p++) {
        int2 rec = paths2[p];
        const float4* xr = xep4 + rec.x * 8;
        const float4* mr = mulp4 + rec.y * 8;
        float4 xv, mv;
        xv = xr[0]; mv = mr[0]; c0.x += xv.x*mv.x; c0.y += xv.y*mv.y; c0.z += xv.z*mv.z; c0.w += xv.w*mv.w;
        xv = xr[1]; mv = mr[1]; c1.x += xv.x*mv.x; c1.y += xv.y*mv.y; c1.z += xv.z*mv.z; c1.w += xv.w*mv.w;
        xv = xr[2]; mv = mr[2]; c2.x += xv.x*mv.x; c2.y += xv.y*mv.y; c2.z += xv.z*mv.z; c2.w += xv.w*mv.w;
        xv = xr[3]; mv = mr[3]; c3.x += xv.x*mv.x; c3.y += xv.y*mv.y; c3.z += xv.z*mv.z; c3.w += xv.w*mv.w;
        xv = xr[4]; mv = mr[4]; c4.x += xv.x*mv.x; c4.y += xv.y*mv.y; c4.z += xv.z*mv.z; c4.w += xv.w*mv.w;
        xv = xr[5]; mv = mr[5]; c5.x += xv.x*mv.x; c5.y += xv.y*mv.y; c5.z += xv.z*mv.z; c5.w += xv.w*mv.w;
        xv = xr[6]; mv = mr[6]; c6.x += xv.x*mv.x; c6.y += xv.y*mv.y; c6.z += xv.z*mv.z; c6.w += xv.w*mv.w;
        xv = xr[7]; mv = mr[7]; c7.x += xv.x*mv.x; c7.y += xv.y*mv.y; c7.z += xv.z*mv.z; c7.w += xv.w*mv.w;
    }
    bool adja = cell[n0] >= 0;
    bool adjb = cell[n0 + 1] >= 0;
    float afa = adja ? 1.f : 0.f;
    float afb = adjb ? 1.f : 0.f;
    float mska = (p1a > p0a || adja) ? 1.f : 0.f;
    float mskb = (p1b > p1a || adjb) ? 1.f : 0.f;
    float* srep = stats + (b & (NREP - 1)) * 80;
#pragma unroll
    for (int ch = 0; ch < 2; ch++) {
        float v[32];
#pragma unroll
        for (int j = 0; j < 16; j++) {
            int dd = ch * 16 + j;
            const float4* wr = (const float4*)(w3q + dd * 36);   // wave-uniform -> s_load, shared by both cells
            float4 wv = wr[8];
            float za = wv.y + afa * wv.x;
            float zb = wv.y + afb * wv.x;
            wv = wr[0]; DOT4(za, a0, wv); DOT4(zb, c0, wv);
            wv = wr[1]; DOT4(za, a1, wv); DOT4(zb, c1, wv);
            wv = wr[2]; DOT4(za, a2, wv); DOT4(zb, c2, wv);
            wv = wr[3]; DOT4(za, a3, wv); DOT4(zb, c3, wv);
            wv = wr[4]; DOT4(za, a4, wv); DOT4(zb, c4, wv);
            wv = wr[5]; DOT4(za, a5, wv); DOT4(zb, c5, wv);
            wv = wr[6]; DOT4(za, a6, wv); DOT4(zb, c6, wv);
            wv = wr[7]; DOT4(za, a7, wv); DOT4(zb, c7, wv);
            v[j] = mska * za + mskb * zb;
            v[16 + j] = mska * za * za + mskb * zb * zb;
        }
#pragma unroll
        for (int i2 = 0; i2 < 32; i2++) v[i2] += __shfl_xor(v[i2], 32);
        redRound<16, 16>(v, t);
        redRound<8, 8>(v, t);
        redRound<4, 4>(v, t);
        redRound<2, 2>(v, t);
        redRound<1, 1>(v, t);
        if (t < 16)      atomicAdd(&srep[ch * 16 + t], v[0]);
        else if (t < 32) atomicAdd(&srep[32 + ch * 16 + t - 16], v[0]);
    }
    {
        float cm2 = mska + mskb;
        for (int off = 32; off >= 1; off >>= 1) cm2 += __shfl_xor(cm2, off);
        if (t == 0) atomicAdd(&srep[64], cm2);
    }
    int last = 0;
    if (t == 0) {
        __threadfence();
        last = (atomicAdd(done, 1) == NBIG - 1) ? 1 : 0;
    }
    last = __shfl(last, 0);
    if (last && t < 32) {
        float sum1 = 0.f, sum2 = 0.f;
        for (int r = 0; r < NREP; r++) {
            sum1 += aread(&stats[r * 80 + t]);
            sum2 += aread(&stats[r * 80 + 32 + t]);
        }
        float cmv = 0.f;
        if (t == 0) for (int r = 0; r < NREP; r++) cmv += aread(&stats[r * 80 + 64]);
        cmv = __shfl(cmv, 0);
        if (cmv < 1.f) cmv = 1.f;
        float mean = sum1 / cmv;
        float var = sum2 / cmv - mean * mean;
        nrm[t] = mean;
        nrm[32 + t] = rsqrtf(fmaxf(var, 0.f) + 1e-5f);
    }
}

// ---------------- output: C at pos pairs via path lists, norm, sym, linear ----------------
__global__ void k_out(const int* __restrict__ pos, const int* __restrict__ pcur,
                      const int2* __restrict__ paths2,
                      const int* __restrict__ cell,
                      const float* __restrict__ xep, const float* __restrict__ mulp,
                      const float* __restrict__ h,
                      const float* __restrict__ w3q,
                      const float* __restrict__ nrm,
                      const float* __restrict__ linf, const float* __restrict__ linb,
                      const int* __restrict__ modep, int cap, void* __restrict__ outp) {
    __shared__ float Cb[4][2][32];
    int t = threadIdx.x;
    int w = t >> 6, lane = t & 63, d = lane & 31, dir = lane >> 5;
    int p = blockIdx.x * 4 + w;
    int a = pos[2 * p], b = pos[2 * p + 1];
    if ((unsigned)a >= (unsigned)NN) a = 0;
    if ((unsigned)b >= (unsigned)NN) b = 0;
    int r = dir ? b : a;
    int cc = dir ? a : b;
    int n = r * NN + cc;
    int p1 = pcur[n];
    int p0 = (n == 0) ? 0 : pcur[n - 1];
    if (p0 > cap) p0 = cap; if (p1 > cap) p1 = cap;
    float acc = 0.f;
    for (int q = p0; q < p1; q++) {
        int2 rec = paths2[q];
        acc += xep[rec.x * 32 + d] * mulp[rec.y * 32 + d];
    }
    Cb[w][dir][d] = acc;
    bool adj = cell[n] >= 0;
    float msk = (p1 > p0 || adj) ? 1.f : 0.f;
    __syncthreads();
    float z = w3q[d * 36 + 33] + (adj ? 1.f : 0.f) * w3q[d * 36 + 32];
#pragma unroll
    for (int c = 0; c < 32; c++) z += Cb[w][dir][c] * w3q[d * 36 + c];
    float zn = fmaxf((z - nrm[d]) * nrm[32 + d], 0.f);
    float zp = __shfl_xor(zn, 32);
    float symd = msk * zn * zp;
    float xxd = h[a * 32 + d] * h[b * 32 + d];
    float contrib = symd * linf[d] + xxd * linf[32 + d];
    for (int off = 16; off >= 1; off >>= 1) contrib += __shfl_xor(contrib, off);
    if (lane == 0) {
        float v = contrib + linb[0];
        v = fminf(fmaxf(v, -1e4f), 1e4f);
        if (*modep) ((bf16*)outp)[p] = __float2bfloat16(v);
        else        ((float*)outp)[p] = v;
    }
}

extern "C" void kernel_launch(void* const* d_in, const int* in_sizes, int n_in,
                              void* d_out, int out_size, void* d_ws, size_t ws_size,
                              hipStream_t stream) {
    const void* px  = d_in[0];  const void* pei = d_in[1];  const void* ppos = d_in[2];
    const void* pemb = d_in[3]; const void* pgW = d_in[4];  const void* pgB  = d_in[5];
    const void* pm1W = d_in[6]; const void* pm1B = d_in[7]; const void* pm2W = d_in[8];
    const void* pm2B = d_in[9]; const void* pm3W = d_in[10]; const void* pm3B = d_in[11];
    const void* plW = d_in[12]; const void* plB = d_in[13];
    {
        int c2048 = 0, c64 = 0, c32 = 0;
        for (int i = 0; i < n_in; i++) {
            int s = in_sizes[i]; const void* p = d_in[i];
            switch (s) {
                case 768:   px = p; break;
                case 49152: pei = p; break;
                case 8192:  ppos = p; break;
                case 3232:  pemb = p; break;
                case 2048:  if (c2048 == 0) pgW = p; else if (c2048 == 1) pm1W = p; else pm2W = p; c2048++; break;
                case 64:    if (c64 == 0) pgB = p; else plW = p; c64++; break;
                case 32:    if (c32 == 0) pm1B = p; else if (c32 == 1) pm2B = p; else pm3B = p; c32++; break;
                case 1056:  pm3W = p; break;
                case 1:     plB = p; break;
                default: break;
            }
        }
    }

    char* ws = (char*)d_ws;
    size_t off = 0;
    auto alloc = [&](size_t bytes) -> void* {
        void* pp = ws + off;
        off += (bytes + 255) & ~(size_t)255;
        return pp;
    };
    int*   cell    = (int*)alloc(NCELL * 4);
    int*   pcur    = (int*)alloc(NCELL * 4);
    int*   rowlen  = (int*)alloc(NN * 4);
    int*   rtot    = (int*)alloc(NN * 4);
    int*   row_base= (int*)alloc(NN * 4);
    int*   row_ptr = (int*)alloc((NN + 1) * 4);
    int*   col_idx = (int*)alloc(NE * 4);
    float* cntv    = (float*)alloc(NE * 4);
    int*   pr_row  = (int*)alloc(NE * 4);
    int*   cursor  = (int*)alloc(NN * 4);
    float* dinv    = (float*)alloc(NN * 4);
    float* h       = (float*)alloc(NN * 32 * 4);
    float* bufA    = (float*)alloc(NN * 32 * 4);
    float* bufB    = (float*)alloc(NN * 32 * 4);
    float* xep     = (float*)alloc(NE * 32 * 4);
    float* mulp    = (float*)alloc(NE * 32 * 4);
    float* stats   = (float*)alloc(NREP * 80 * 4);
    float* nrm     = (float*)alloc(64 * 4);
    float* nrm0    = (float*)alloc(64 * 4);
    float* nrm1    = (float*)alloc(64 * 4);
    float* gwf     = (float*)alloc(2048 * 4);
    float* gbf     = (float*)alloc(64 * 4);
    float* w1f     = (float*)alloc(2048 * 4);
    float* b1f     = (float*)alloc(32 * 4);
    float* w2f     = (float*)alloc(2048 * 4);
    float* b2f     = (float*)alloc(32 * 4);
    float* w3q     = (float*)alloc(32 * 36 * 4);
    float* linf    = (float*)alloc(64 * 4);
    float* linb    = (float*)alloc(4);
    int*   modeg   = (int*)alloc(4);
    int*   dcs     = (int*)alloc(8 * 4);
    size_t remain = (ws_size > off) ? (ws_size - off) : 0;
    int cap = (int)(remain / 8);
    if (cap > (1 << 20)) cap = (1 << 20);
    int2*  paths2  = (int2*)alloc((size_t)cap * 8);

    hipMemsetAsync(cell, 0, (size_t)NCELL * 4, stream);
    k_conv<<<2, 256, 0, stream>>>(pgW, pgB, pm1W, pm1B, pm2W, pm2B, pm3W, pm3B, plW, plB,
                                  pemb, stats, cursor, rowlen, rtot, dcs, modeg,
                                  gwf, gbf, w1f, b1f, w2f, b2f, w3q, linf, linb);
    k_scatter<<<96, 256, 0, stream>>>((const int*)pei, cell, rowlen, row_ptr, dinv, &dcs[0]);
    k_fill<<<NBLK + 96, 256, 0, stream>>>(cell, row_ptr, cursor, col_idx, cntv, pr_row,
                                          rowlen, rtot, (const int*)px, pemb, modeg, bufA);
    k_aggmw0<<<1 + 96, 256, 0, stream>>>(rtot, row_base, row_ptr, col_idx, bufA, dinv, gwf, gbf, bufB);
    k_hist<<<NN + 1, 256, 0, stream>>>(row_ptr, col_idx, row_base, pcur, paths2, cap, bufB, nrm0);
    k_aggmw1<<<96, 256, 0, stream>>>(row_ptr, col_idx, bufB, nrm0, dinv, gwf, gbf, bufA);
    k_st1<<<1, 256, 0, stream>>>(bufA, nrm1);
    k_emlp<<<3072 + 96, 256, 0, stream>>>(bufA, nrm1, row_ptr, col_idx, pr_row, cntv,
                                          w1f, b1f, w2f, b2f, xep, mulp, h);
    k_big<<<NBIG, 64, 0, stream>>>(pcur, paths2, cell, (const float4*)xep, (const float4*)mulp,
                                   w3q, stats, &dcs[1], nrm, cap);
    k_out<<<NPOS / 4, 256, 0, stream>>>((const int*)ppos, pcur, paths2, cell, xep, mulp, h,
                                        w3q, nrm, linf, linb, modeg, cap, d_out);
}

// Round 14
// 307.915 us; speedup vs baseline: 1.2872x; 1.2872x over previous
//
#include <hip/hip_runtime.h>
#include <hip/hip_bf16.h>

#define NN 768
#define NE 24576
#define NPOS 4096
#define NCELL (NN*NN)   // 589824
#define NBLK 2304
#define NBLK2 1152      // k_big: 256 threads, 512 cells/block, 2 cells/thread
#define NREP 16

typedef __hip_bfloat16 bf16;

__device__ __forceinline__ float ldf(const void* p, int i, int mode) {
    return mode ? __bfloat162float(((const bf16*)p)[i]) : ((const float*)p)[i];
}
__device__ __forceinline__ float aread(float* p) { return atomicAdd(p, 0.f); }
__device__ __forceinline__ int areadi(int* p) { return atomicAdd(p, 0); }

template<int D, int HALF>
__device__ __forceinline__ void redRound(float* v, int lane) {
#pragma unroll
    for (int i = 0; i < HALF; i++) {
        float snd = (lane & D) ? v[i] : v[i + HALF];
        float r = __shfl_xor(snd, D);
        v[i] = ((lane & D) ? v[i + HALF] : v[i]) + r;
    }
}

#define DOT4(Z, A, W) Z += A.x * W.x + A.y * W.y + A.z * W.z + A.w * W.w
#define GATH(rec, q0,q1,q2,q3,q4,q5,q6,q7) { \
    const float4* xr = xep4 + (rec).x * 8; \
    const float4* mr = mulp4 + (rec).y * 8; \
    float4 xv, mv; \
    xv = xr[0]; mv = mr[0]; q0.x += xv.x*mv.x; q0.y += xv.y*mv.y; q0.z += xv.z*mv.z; q0.w += xv.w*mv.w; \
    xv = xr[1]; mv = mr[1]; q1.x += xv.x*mv.x; q1.y += xv.y*mv.y; q1.z += xv.z*mv.z; q1.w += xv.w*mv.w; \
    xv = xr[2]; mv = mr[2]; q2.x += xv.x*mv.x; q2.y += xv.y*mv.y; q2.z += xv.z*mv.z; q2.w += xv.w*mv.w; \
    xv = xr[3]; mv = mr[3]; q3.x += xv.x*mv.x; q3.y += xv.y*mv.y; q3.z += xv.z*mv.z; q3.w += xv.w*mv.w; \
    xv = xr[4]; mv = mr[4]; q4.x += xv.x*mv.x; q4.y += xv.y*mv.y; q4.z += xv.z*mv.z; q4.w += xv.w*mv.w; \
    xv = xr[5]; mv = mr[5]; q5.x += xv.x*mv.x; q5.y += xv.y*mv.y; q5.z += xv.z*mv.z; q5.w += xv.w*mv.w; \
    xv = xr[6]; mv = mr[6]; q6.x += xv.x*mv.x; q6.y += xv.y*mv.y; q6.z += xv.z*mv.z; q6.w += xv.w*mv.w; \
    xv = xr[7]; mv = mr[7]; q7.x += xv.x*mv.x; q7.y += xv.y*mv.y; q7.z += xv.z*mv.z; q7.w += xv.w*mv.w; }

// ---------------- conv (block 0) + aux clear (block 1) ----------------
__global__ void k_conv(const void* __restrict__ gW, const void* __restrict__ gB,
                       const void* __restrict__ m1W, const void* __restrict__ m1B,
                       const void* __restrict__ m2W, const void* __restrict__ m2B,
                       const void* __restrict__ m3W, const void* __restrict__ m3B,
                       const void* __restrict__ lW,  const void* __restrict__ lB,
                       const void* __restrict__ emb,
                       float* __restrict__ stats, float* __restrict__ stats1,
                       int* __restrict__ cursor,
                       int* __restrict__ rowlen, int* __restrict__ rtot, int* __restrict__ dcs,
                       int* __restrict__ modeg,
                       float* __restrict__ gwf, float* __restrict__ gbf,
                       float* __restrict__ w1f, float* __restrict__ b1f,
                       float* __restrict__ w2f, float* __restrict__ b2f,
                       float* __restrict__ w3q, float* __restrict__ linf, float* __restrict__ linb) {
    int t = threadIdx.x;
    if (blockIdx.x == 1) {
        for (int i = t; i < NN; i += 256) { cursor[i] = 0; rowlen[i] = 0; rtot[i] = 0; }
        for (int i = t; i < NREP * 80; i += 256) { stats[i] = 0.f; stats1[i] = 0.f; }
        if (t < 8) dcs[t] = 0;
        return;
    }
    __shared__ int bad;
    if (t == 0) bad = 0;
    __syncthreads();
    int local = 0;
    for (int i = t; i < 3232; i += 256) {
        float a = fabsf(__bfloat162float(((const bf16*)emb)[i]));
        if (!(a < 100.f)) local = 1;
    }
    if (local) atomicOr(&bad, 1);
    __syncthreads();
    int mode = bad ? 0 : 1;
    if (t == 0) *modeg = mode;
    for (int i = t; i < 2048; i += 256) {
        gwf[i] = ldf(gW, i, mode);
        w1f[i] = ldf(m1W, i, mode);
        w2f[i] = ldf(m2W, i, mode);
    }
    for (int i = t; i < 64; i += 256) { gbf[i] = ldf(gB, i, mode); linf[i] = ldf(lW, i, mode); }
    if (t < 32) { b1f[t] = ldf(m1B, t, mode); b2f[t] = ldf(m2B, t, mode); }
    // w3q row d (stride 36 floats, 16B-aligned): [W3[0..31][d], ind, b3, 0, 0]
    for (int i = t; i < 1056; i += 256) { int c = i >> 5, d = i & 31; w3q[d * 36 + c] = ldf(m3W, i, mode); }
    if (t < 32) { w3q[t * 36 + 33] = ldf(m3B, t, mode); w3q[t * 36 + 34] = 0.f; w3q[t * 36 + 35] = 0.f; }
    if (t == 0) linb[0] = ldf(lB, 0, mode);
}

// ---------------- edge scatter; last block: row scan + dinv ----------------
__global__ void k_scatter(const int* __restrict__ ei, int* __restrict__ cell, int* __restrict__ rowlen,
                          int* __restrict__ row_ptr, float* __restrict__ dinv, int* __restrict__ dc) {
    __shared__ int amlast;
    __shared__ int sI[256];
    int t = threadIdx.x;
    int e = blockIdx.x * 256 + t;
    int a = ei[e], b = ei[NE + e];
    if ((unsigned)a < (unsigned)NN && (unsigned)b < (unsigned)NN) {
        int old = atomicAdd(&cell[a * NN + b], 1);
        if (old == 0) atomicAdd(&rowlen[a], 1);
    }
    __syncthreads();
    if (t == 0) { __threadfence(); amlast = (atomicAdd(dc, 1) == 95) ? 1 : 0; }
    __syncthreads();
    if (!amlast) return;
    int i0 = 3 * t;
    int r0 = areadi(&rowlen[i0]), r1 = areadi(&rowlen[i0 + 1]), r2 = areadi(&rowlen[i0 + 2]);
    dinv[i0]     = rsqrtf((float)r0 + 1.f);
    dinv[i0 + 1] = rsqrtf((float)r1 + 1.f);
    dinv[i0 + 2] = rsqrtf((float)r2 + 1.f);
    int s3 = r0 + r1 + r2;
    sI[t] = s3;
    __syncthreads();
    for (int off = 1; off < 256; off <<= 1) {
        int tmp = (t >= off) ? sI[t - off] : 0;
        __syncthreads();
        sI[t] += tmp;
        __syncthreads();
    }
    int excl = sI[t] - s3;
    row_ptr[i0] = excl;
    row_ptr[i0 + 1] = excl + r0;
    row_ptr[i0 + 2] = excl + r0 + r1;
    if (t == 255) row_ptr[NN] = sI[255];
}

// ---------------- CSR fill + rtot (b<2304) || emb gather E -> bufA (b>=2304) ----------------
__global__ void k_fill(int* __restrict__ cell, const int* __restrict__ row_ptr, int* __restrict__ cursor,
                       int* __restrict__ col_idx, float* __restrict__ cntv, int* __restrict__ pr_row,
                       const int* __restrict__ rowlen, int* __restrict__ rtot,
                       const int* __restrict__ x, const void* __restrict__ emb,
                       const int* __restrict__ modep, float* __restrict__ bufA) {
    int t = threadIdx.x;
    int b = blockIdx.x;
    if (b < NBLK) {
        int idx = b * 256 + t;
        int i = idx / NN;
        int j = idx - i * NN;
        int cv = cell[idx];
        if (cv > 0) {
            int p = row_ptr[i] + atomicAdd(&cursor[i], 1);
            col_idx[p] = j; cntv[p] = (float)cv; pr_row[p] = i;
            cell[idx] = p;
            atomicAdd(&rtot[i], rowlen[j]);
        } else cell[idx] = -1;
    } else {
        int idx = (b - NBLK) * 256 + t;   // 768*32
        int i = idx >> 5, k = idx & 31;
        int xi = x[i]; if (xi < 0) xi = 0; if (xi > 100) xi = 100;
        bufA[idx] = ldf(emb, xi * 32 + k, *modep);
    }
}

// ---------------- b==0: row_base scan || b>=1: agg(E) then @W0 -> bufB ----------------
__global__ void k_aggmw0(const int* __restrict__ rtot, int* __restrict__ row_base,
                         const int* __restrict__ row_ptr, const int* __restrict__ col_idx,
                         const float* __restrict__ bufA, const float* __restrict__ dinv,
                         const float* __restrict__ gwf, const float* __restrict__ gbf,
                         float* __restrict__ bufB) {
    int t = threadIdx.x;
    if (blockIdx.x == 0) {
        __shared__ int sI[256];
        int r3[3]; int s3 = 0;
#pragma unroll
        for (int q = 0; q < 3; q++) { r3[q] = rtot[3 * t + q]; s3 += r3[q]; }
        sI[t] = s3;
        __syncthreads();
        for (int off = 1; off < 256; off <<= 1) {
            int tmp = (t >= off) ? sI[t - off] : 0;
            __syncthreads();
            sI[t] += tmp;
            __syncthreads();
        }
        int run = sI[t] - s3;
        row_base[3 * t] = run;
        row_base[3 * t + 1] = run + r3[0];
        row_base[3 * t + 2] = run + r3[0] + r3[1];
        return;
    }
    __shared__ float sg[8][32];
    int li = t >> 5, k = t & 31;
    int i = (blockIdx.x - 1) * 8 + li;
    int base = row_ptr[i], len = row_ptr[i + 1] - base;
    float di = dinv[i];
    float acc = di * bufA[i * 32 + k];
    for (int e = 0; e < len; e++) {
        int c = col_idx[base + e];
        acc += dinv[c] * bufA[c * 32 + k];
    }
    sg[li][k] = di * acc;
    __syncthreads();
    int d = k;
    float s = gbf[d];
#pragma unroll
    for (int kk = 0; kk < 32; kk++) s += sg[li][kk] * gwf[kk * 32 + d];
    bufB[i * 32 + d] = s;
}

// ---------------- per-row path histogram (b<768) || nrm0 from bufB (b==768) ----------------
__global__ void k_hist(const int* __restrict__ row_ptr, const int* __restrict__ col_idx,
                       const int* __restrict__ row_base,
                       int* __restrict__ pcur, int2* __restrict__ paths2, int cap,
                       const float* __restrict__ bufB, float* __restrict__ nrm0) {
    int t = threadIdx.x;
    if (blockIdx.x == NN) {
        __shared__ float r1[256], r2[256];
        int dd = t & 31, g = t >> 5;
        float s = 0.f, s2 = 0.f;
        for (int r = g; r < NN; r += 8) { float v = bufB[r * 32 + dd]; s += v; s2 += v * v; }
        r1[t] = s; r2[t] = s2;
        __syncthreads();
        if (t < 32) {
            float a = 0.f, b2 = 0.f;
            for (int k = 0; k < 8; k++) { a += r1[k * 32 + t]; b2 += r2[k * 32 + t]; }
            float mean = a / (float)NN;
            float var = b2 / (float)NN - mean * mean;
            nrm0[t] = mean;
            nrm0[32 + t] = rsqrtf(fmaxf(var, 0.f) + 1e-5f);
        }
        return;
    }
    __shared__ int hist[NN];
    __shared__ int sc[256];
    int i = blockIdx.x;
    int base = row_ptr[i], len = row_ptr[i + 1] - base;
    int rb = row_base[i];
    int wave = t >> 6, lane = t & 63;
    for (int j = t; j < NN; j += 256) hist[j] = 0;
    __syncthreads();
    for (int ee = wave; ee < len; ee += 4) {
        int k = col_idx[base + ee];
        int kb = row_ptr[k], ke = row_ptr[k + 1];
        for (int e = kb + lane; e < ke; e += 64) atomicAdd(&hist[col_idx[e]], 1);
    }
    __syncthreads();
    int h0 = hist[3 * t], h1 = hist[3 * t + 1], h2 = hist[3 * t + 2];
    int s3 = h0 + h1 + h2;
    sc[t] = s3;
    __syncthreads();
    for (int off = 1; off < 256; off <<= 1) {
        int tmp = (t >= off) ? sc[t - off] : 0;
        __syncthreads();
        sc[t] += tmp;
        __syncthreads();
    }
    int excl = sc[t] - s3;
    int n0 = i * NN + 3 * t;
    pcur[n0]     = rb + excl + h0;            // absolute END offsets
    pcur[n0 + 1] = rb + excl + h0 + h1;
    pcur[n0 + 2] = rb + excl + h0 + h1 + h2;
    hist[3 * t] = excl;
    hist[3 * t + 1] = excl + h0;
    hist[3 * t + 2] = excl + h0 + h1;
    __syncthreads();
    for (int ee = wave; ee < len; ee += 4) {
        int e1 = base + ee;
        int k = col_idx[e1];
        int kb = row_ptr[k], ke = row_ptr[k + 1];
        for (int e = kb + lane; e < ke; e += 64) {
            int j = col_idx[e];
            int slot = rb + atomicAdd(&hist[j], 1);
            if (slot < cap) paths2[slot] = make_int2(e1, e);
        }
    }
}

// ---------------- agg(g(bufB,nrm0)) then @W1 -> bufA ; accumulate stats1 partials ----------------
__global__ void k_aggmw1(const int* __restrict__ row_ptr, const int* __restrict__ col_idx,
                         const float* __restrict__ bufB, const float* __restrict__ nrm0,
                         const float* __restrict__ dinv,
                         const float* __restrict__ gwf, const float* __restrict__ gbf,
                         float* __restrict__ bufA, float* __restrict__ stats1) {
    __shared__ float sg[8][32];
    int t = threadIdx.x;
    int li = t >> 5, k = t & 31;
    int i = blockIdx.x * 8 + li;
    float mk = nrm0[k], rk = nrm0[32 + k];
    int base = row_ptr[i], len = row_ptr[i + 1] - base;
    float di = dinv[i];
    float acc = di * fmaxf((bufB[i * 32 + k] - mk) * rk, 0.f);
    for (int e = 0; e < len; e++) {
        int c = col_idx[base + e];
        acc += dinv[c] * fmaxf((bufB[c * 32 + k] - mk) * rk, 0.f);
    }
    sg[li][k] = di * acc;
    __syncthreads();
    int d = k;
    const float* W = gwf + 1024;
    float s = gbf[32 + d];
#pragma unroll
    for (int kk = 0; kk < 32; kk++) s += sg[li][kk] * W[kk * 32 + d];
    bufA[i * 32 + d] = s;
    __syncthreads();
    sg[li][d] = s;   // reuse LDS for column partials
    __syncthreads();
    if (t < 32) {
        float ps = 0.f, ps2 = 0.f;
#pragma unroll
        for (int q = 0; q < 8; q++) { float v = sg[q][t]; ps += v; ps2 += v * v; }
        float* rep = stats1 + (blockIdx.x & (NREP - 1)) * 80;
        atomicAdd(&rep[t], ps);
        atomicAdd(&rep[32 + t], ps2);
    }
}

// ---------------- edge MLP (b<3072) || h write (b>=3072); nrm1 computed locally ----------------
__global__ void k_emlp(const float* __restrict__ bufA, const float* __restrict__ stats1,
                       const int* __restrict__ row_ptr, const int* __restrict__ col_idx,
                       const int* __restrict__ pr_row, const float* __restrict__ cntv,
                       const float* __restrict__ w1f, const float* __restrict__ b1f,
                       const float* __restrict__ w2f, const float* __restrict__ b2f,
                       float* __restrict__ xep, float* __restrict__ mulp, float* __restrict__ h) {
    __shared__ float nmean[32], nrstd[32];
    int t = threadIdx.x;
    int b = blockIdx.x;
    if (t < 32) {
        float s = 0.f, s2 = 0.f;
#pragma unroll
        for (int r = 0; r < NREP; r++) { s += stats1[r * 80 + t]; s2 += stats1[r * 80 + 32 + t]; }
        float mean = s / (float)NN;
        float var = s2 / (float)NN - mean * mean;
        nmean[t] = mean;
        nrstd[t] = rsqrtf(fmaxf(var, 0.f) + 1e-5f);
    }
    __syncthreads();
    if (b < 3072) {
        int d = t & 31;
        int p = b * 8 + (t >> 5);
        if (p >= row_ptr[NN]) {
            if (p < NE) { xep[p * 32 + d] = 0.f; mulp[p * 32 + d] = 0.f; }
            return;
        }
        int i = pr_row[p], j = col_idx[p];
        float a1 = b1f[d], a2 = b2f[d];
#pragma unroll
        for (int c = 0; c < 32; c++) {
            float hv = fmaxf((bufA[i * 32 + c] - nmean[c]) * nrstd[c], 0.f);
            a1 += hv * w1f[c * 32 + d];
            a2 += hv * w2f[c * 32 + d];
        }
#pragma unroll
        for (int c = 0; c < 32; c++) {
            float hv = fmaxf((bufA[j * 32 + c] - nmean[c]) * nrstd[c], 0.f);
            a1 += hv * w1f[(32 + c) * 32 + d];
            a2 += hv * w2f[(32 + c) * 32 + d];
        }
        float cv = cntv[p];
        xep[p * 32 + d]  = cv * fmaxf(a1, 0.f);
        mulp[p * 32 + d] = cv * fmaxf(a2, 0.f);
    } else {
        int idx = (b - 3072) * 256 + t;
        int d = idx & 31;
        h[idx] = fmaxf((bufA[idx] - nmean[d]) * nrstd[d], 0.f);
    }
}

// ---------------- fused big: 256 thr, 2 cells/thread, INTERLEAVED gathers ----------------
__global__ __launch_bounds__(256, 3) void k_big(const int* __restrict__ pcur,
                                                const int2* __restrict__ paths2,
                                                const int* __restrict__ cell,
                                                const float4* __restrict__ xep4, const float4* __restrict__ mulp4,
                                                const float* __restrict__ w3q,
                                                float* __restrict__ stats, int* __restrict__ done,
                                                float* __restrict__ nrm, int cap) {
    __shared__ float sS1[32], sS2[32];
    __shared__ float sCm;
    __shared__ int amlast;
    int t = threadIdx.x, lane = t & 63;
    int b = blockIdx.x;
    int n0 = b * 512 + 2 * t;
    if (t == 0) sCm = 0.f;
    if (t < 32) { sS1[t] = 0.f; sS2[t] = 0.f; }
    __syncthreads();
    int p0a = (n0 == 0) ? 0 : pcur[n0 - 1];
    int p1a = pcur[n0];
    int p1b = pcur[n0 + 1];
    if (p0a > cap) p0a = cap; if (p1a > cap) p1a = cap; if (p1b > cap) p1b = cap;
    int lenA = p1a - p0a, lenB = p1b - p1a;
    int lim = (lenA > lenB) ? lenA : lenB;
    float4 a0 = {0.f,0.f,0.f,0.f}, a1 = a0, a2 = a0, a3 = a0, a4 = a0, a5 = a0, a6 = a0, a7 = a0;
    float4 c0 = a0, c1 = a0, c2 = a0, c3 = a0, c4 = a0, c5 = a0, c6 = a0, c7 = a0;
    for (int q = 0; q < lim; q++) {
        // interleaved: both cells' gathers in flight each iteration
        int2 recA, recB;
        bool doA = q < lenA, doB = q < lenB;
        if (doA) recA = paths2[p0a + q];
        if (doB) recB = paths2[p1a + q];
        if (doA) GATH(recA, a0, a1, a2, a3, a4, a5, a6, a7);
        if (doB) GATH(recB, c0, c1, c2, c3, c4, c5, c6, c7);
    }
    bool adja = cell[n0] >= 0;
    bool adjb = cell[n0 + 1] >= 0;
    float afa = adja ? 1.f : 0.f;
    float afb = adjb ? 1.f : 0.f;
    float mska = (lenA > 0 || adja) ? 1.f : 0.f;
    float mskb = (lenB > 0 || adjb) ? 1.f : 0.f;
#pragma unroll
    for (int ch = 0; ch < 2; ch++) {
        float v[32];
#pragma unroll
        for (int j = 0; j < 16; j++) {
            int dd = ch * 16 + j;
            const float4* wr = (const float4*)(w3q + dd * 36);   // wave-uniform -> s_load, shared by both cells
            float4 wv = wr[8];
            float za = wv.y + afa * wv.x;
            float zb = wv.y + afb * wv.x;
            wv = wr[0]; DOT4(za, a0, wv); DOT4(zb, c0, wv);
            wv = wr[1]; DOT4(za, a1, wv); DOT4(zb, c1, wv);
            wv = wr[2]; DOT4(za, a2, wv); DOT4(zb, c2, wv);
            wv = wr[3]; DOT4(za, a3, wv); DOT4(zb, c3, wv);
            wv = wr[4]; DOT4(za, a4, wv); DOT4(zb, c4, wv);
            wv = wr[5]; DOT4(za, a5, wv); DOT4(zb, c5, wv);
            wv = wr[6]; DOT4(za, a6, wv); DOT4(zb, c6, wv);
            wv = wr[7]; DOT4(za, a7, wv); DOT4(zb, c7, wv);
            v[j] = mska * za + mskb * zb;
            v[16 + j] = mska * za * za + mskb * zb * zb;
        }
#pragma unroll
        for (int i2 = 0; i2 < 32; i2++) v[i2] += __shfl_xor(v[i2], 32);
        redRound<16, 16>(v, lane);
        redRound<8, 8>(v, lane);
        redRound<4, 4>(v, lane);
        redRound<2, 2>(v, lane);
        redRound<1, 1>(v, lane);
        if (lane < 32) {
            if (lane < 16) atomicAdd(&sS1[ch * 16 + lane], v[0]);
            else           atomicAdd(&sS2[ch * 16 + lane - 16], v[0]);
        }
    }
    {
        float cm2 = mska + mskb;
        for (int off = 32; off >= 1; off >>= 1) cm2 += __shfl_xor(cm2, off);
        if (lane == 0) atomicAdd(&sCm, cm2);
    }
    __syncthreads();
    float* srep = stats + (b & (NREP - 1)) * 80;
    if (t < 32) {
        atomicAdd(&srep[t], sS1[t]);
        atomicAdd(&srep[32 + t], sS2[t]);
    }
    if (t == 32) atomicAdd(&srep[64], sCm);
    __syncthreads();
    if (t == 0) {
        __threadfence();
        amlast = (atomicAdd(done, 1) == NBLK2 - 1) ? 1 : 0;
    }
    __syncthreads();
    if (amlast && t < 32) {
        float sum1 = 0.f, sum2 = 0.f;
        for (int r = 0; r < NREP; r++) {
            sum1 += aread(&stats[r * 80 + t]);
            sum2 += aread(&stats[r * 80 + 32 + t]);
        }
        float cmv = 0.f;
        for (int r = 0; r < NREP; r++) cmv += aread(&stats[r * 80 + 64]);
        if (cmv < 1.f) cmv = 1.f;
        float mean = sum1 / cmv;
        float var = sum2 / cmv - mean * mean;
        nrm[t] = mean;
        nrm[32 + t] = rsqrtf(fmaxf(var, 0.f) + 1e-5f);
    }
}

// ---------------- output: C at pos pairs via path lists, norm, sym, linear ----------------
__global__ void k_out(const int* __restrict__ pos, const int* __restrict__ pcur,
                      const int2* __restrict__ paths2,
                      const int* __restrict__ cell,
                      const float* __restrict__ xep, const float* __restrict__ mulp,
                      const float* __restrict__ h,
                      const float* __restrict__ w3q,
                      const float* __restrict__ nrm,
                      const float* __restrict__ linf, const float* __restrict__ linb,
                      const int* __restrict__ modep, int cap, void* __restrict__ outp) {
    __shared__ float Cb[4][2][32];
    int t = threadIdx.x;
    int w = t >> 6, lane = t & 63, d = lane & 31, dir = lane >> 5;
    int p = blockIdx.x * 4 + w;
    int a = pos[2 * p], b = pos[2 * p + 1];
    if ((unsigned)a >= (unsigned)NN) a = 0;
    if ((unsigned)b >= (unsigned)NN) b = 0;
    int r = dir ? b : a;
    int cc = dir ? a : b;
    int n = r * NN + cc;
    int p1 = pcur[n];
    int p0 = (n == 0) ? 0 : pcur[n - 1];
    if (p0 > cap) p0 = cap; if (p1 > cap) p1 = cap;
    float acc = 0.f;
    for (int q = p0; q < p1; q++) {
        int2 rec = paths2[q];
        acc += xep[rec.x * 32 + d] * mulp[rec.y * 32 + d];
    }
    Cb[w][dir][d] = acc;
    bool adj = cell[n] >= 0;
    float msk = (p1 > p0 || adj) ? 1.f : 0.f;
    __syncthreads();
    float z = w3q[d * 36 + 33] + (adj ? 1.f : 0.f) * w3q[d * 36 + 32];
#pragma unroll
    for (int c = 0; c < 32; c++) z += Cb[w][dir][c] * w3q[d * 36 + c];
    float zn = fmaxf((z - nrm[d]) * nrm[32 + d], 0.f);
    float zp = __shfl_xor(zn, 32);
    float symd = msk * zn * zp;
    float xxd = h[a * 32 + d] * h[b * 32 + d];
    float contrib = symd * linf[d] + xxd * linf[32 + d];
    for (int off = 16; off >= 1; off >>= 1) contrib += __shfl_xor(contrib, off);
    if (lane == 0) {
        float v = contrib + linb[0];
        v = fminf(fmaxf(v, -1e4f), 1e4f);
        if (*modep) ((bf16*)outp)[p] = __float2bfloat16(v);
        else        ((float*)outp)[p] = v;
    }
}

extern "C" void kernel_launch(void* const* d_in, const int* in_sizes, int n_in,
                              void* d_out, int out_size, void* d_ws, size_t ws_size,
                              hipStream_t stream) {
    const void* px  = d_in[0];  const void* pei = d_in[1];  const void* ppos = d_in[2];
    const void* pemb = d_in[3]; const void* pgW = d_in[4];  const void* pgB  = d_in[5];
    const void* pm1W = d_in[6]; const void* pm1B = d_in[7]; const void* pm2W = d_in[8];
    const void* pm2B = d_in[9]; const void* pm3W = d_in[10]; const void* pm3B = d_in[11];
    const void* plW = d_in[12]; const void* plB = d_in[13];
    {
        int c2048 = 0, c64 = 0, c32 = 0;
        for (int i = 0; i < n_in; i++) {
            int s = in_sizes[i]; const void* p = d_in[i];
            switch (s) {
                case 768:   px = p; break;
                case 49152: pei = p; break;
                case 8192:  ppos = p; break;
                case 3232:  pemb = p; break;
                case 2048:  if (c2048 == 0) pgW = p; else if (c2048 == 1) pm1W = p; else pm2W = p; c2048++; break;
                case 64:    if (c64 == 0) pgB = p; else plW = p; c64++; break;
                case 32:    if (c32 == 0) pm1B = p; else if (c32 == 1) pm2B = p; else pm3B = p; c32++; break;
                case 1056:  pm3W = p; break;
                case 1:     plB = p; break;
                default: break;
            }
        }
    }

    char* ws = (char*)d_ws;
    size_t off = 0;
    auto alloc = [&](size_t bytes) -> void* {
        void* pp = ws + off;
        off += (bytes + 255) & ~(size_t)255;
        return pp;
    };
    int*   cell    = (int*)alloc(NCELL * 4);
    int*   pcur    = (int*)alloc(NCELL * 4);
    int*   rowlen  = (int*)alloc(NN * 4);
    int*   rtot    = (int*)alloc(NN * 4);
    int*   row_base= (int*)alloc(NN * 4);
    int*   row_ptr = (int*)alloc((NN + 1) * 4);
    int*   col_idx = (int*)alloc(NE * 4);
    float* cntv    = (float*)alloc(NE * 4);
    int*   pr_row  = (int*)alloc(NE * 4);
    int*   cursor  = (int*)alloc(NN * 4);
    float* dinv    = (float*)alloc(NN * 4);
    float* h       = (float*)alloc(NN * 32 * 4);
    float* bufA    = (float*)alloc(NN * 32 * 4);
    float* bufB    = (float*)alloc(NN * 32 * 4);
    float* xep     = (float*)alloc(NE * 32 * 4);
    float* mulp    = (float*)alloc(NE * 32 * 4);
    float* stats   = (float*)alloc(NREP * 80 * 4);
    float* stats1  = (float*)alloc(NREP * 80 * 4);
    float* nrm     = (float*)alloc(64 * 4);
    float* nrm0    = (float*)alloc(64 * 4);
    float* gwf     = (float*)alloc(2048 * 4);
    float* gbf     = (float*)alloc(64 * 4);
    float* w1f     = (float*)alloc(2048 * 4);
    float* b1f     = (float*)alloc(32 * 4);
    float* w2f     = (float*)alloc(2048 * 4);
    float* b2f     = (float*)alloc(32 * 4);
    float* w3q     = (float*)alloc(32 * 36 * 4);
    float* linf    = (float*)alloc(64 * 4);
    float* linb    = (float*)alloc(4);
    int*   modeg   = (int*)alloc(4);
    int*   dcs     = (int*)alloc(8 * 4);
    size_t remain = (ws_size > off) ? (ws_size - off) : 0;
    int cap = (int)(remain / 8);
    if (cap > (1 << 20)) cap = (1 << 20);
    int2*  paths2  = (int2*)alloc((size_t)cap * 8);

    hipMemsetAsync(cell, 0, (size_t)NCELL * 4, stream);
    k_conv<<<2, 256, 0, stream>>>(pgW, pgB, pm1W, pm1B, pm2W, pm2B, pm3W, pm3B, plW, plB,
                                  pemb, stats, stats1, cursor, rowlen, rtot, dcs, modeg,
                                  gwf, gbf, w1f, b1f, w2f, b2f, w3q, linf, linb);
    k_scatter<<<96, 256, 0, stream>>>((const int*)pei, cell, rowlen, row_ptr, dinv, &dcs[0]);
    k_fill<<<NBLK + 96, 256, 0, stream>>>(cell, row_ptr, cursor, col_idx, cntv, pr_row,
                                          rowlen, rtot, (const int*)px, pemb, modeg, bufA);
    k_aggmw0<<<1 + 96, 256, 0, stream>>>(rtot, row_base, row_ptr, col_idx, bufA, dinv, gwf, gbf, bufB);
    k_hist<<<NN + 1, 256, 0, stream>>>(row_ptr, col_idx, row_base, pcur, paths2, cap, bufB, nrm0);
    k_aggmw1<<<96, 256, 0, stream>>>(row_ptr, col_idx, bufB, nrm0, dinv, gwf, gbf, bufA, stats1);
    k_emlp<<<3072 + 96, 256, 0, stream>>>(bufA, stats1, row_ptr, col_idx, pr_row, cntv,
                                          w1f, b1f, w2f, b2f, xep, mulp, h);
    k_big<<<NBLK2, 256, 0, stream>>>(pcur, paths2, cell, (const float4*)xep, (const float4*)mulp,
                                     w3q, stats, &dcs[1], nrm, cap);
    k_out<<<NPOS / 4, 256, 0, stream>>>((const int*)ppos, pcur, paths2, cell, xep, mulp, h,
                                        w3q, nrm, linf, linb, modeg, cap, d_out);
}

// Round 15
// 299.848 us; speedup vs baseline: 1.3218x; 1.0269x over previous
//
#include <hip/hip_runtime.h>
#include <hip/hip_bf16.h>

#define NN 768
#define NE 24576
#define NPOS 4096
#define NCELL (NN*NN)   // 589824
#define NBLK 2304
#define NBLK2 1152      // k_big: 256 threads, 512 cells/block, 2 cells/thread
#define NREP 16

typedef __hip_bfloat16 bf16;

__device__ __forceinline__ float ldf(const void* p, int i, int mode) {
    return mode ? __bfloat162float(((const bf16*)p)[i]) : ((const float*)p)[i];
}
__device__ __forceinline__ float aread(float* p) { return atomicAdd(p, 0.f); }
__device__ __forceinline__ int areadi(int* p) { return atomicAdd(p, 0); }

template<int D, int HALF>
__device__ __forceinline__ void redRound(float* v, int lane) {
#pragma unroll
    for (int i = 0; i < HALF; i++) {
        float snd = (lane & D) ? v[i] : v[i + HALF];
        float r = __shfl_xor(snd, D);
        v[i] = ((lane & D) ? v[i + HALF] : v[i]) + r;
    }
}

#define DOT4(Z, A, W) Z += A.x * W.x + A.y * W.y + A.z * W.z + A.w * W.w

// load-all-then-FMA gather: 16 float4 loads issued before any FMA consumes them
#define GATH(rec, q0,q1,q2,q3,q4,q5,q6,q7) { \
    const float4* xr = xep4 + (rec).x * 8; \
    const float4* mr = mulp4 + (rec).y * 8; \
    float4 xv0 = xr[0], xv1 = xr[1], xv2 = xr[2], xv3 = xr[3]; \
    float4 xv4 = xr[4], xv5 = xr[5], xv6 = xr[6], xv7 = xr[7]; \
    float4 mv0 = mr[0], mv1 = mr[1], mv2 = mr[2], mv3 = mr[3]; \
    float4 mv4 = mr[4], mv5 = mr[5], mv6 = mr[6], mv7 = mr[7]; \
    q0.x += xv0.x*mv0.x; q0.y += xv0.y*mv0.y; q0.z += xv0.z*mv0.z; q0.w += xv0.w*mv0.w; \
    q1.x += xv1.x*mv1.x; q1.y += xv1.y*mv1.y; q1.z += xv1.z*mv1.z; q1.w += xv1.w*mv1.w; \
    q2.x += xv2.x*mv2.x; q2.y += xv2.y*mv2.y; q2.z += xv2.z*mv2.z; q2.w += xv2.w*mv2.w; \
    q3.x += xv3.x*mv3.x; q3.y += xv3.y*mv3.y; q3.z += xv3.z*mv3.z; q3.w += xv3.w*mv3.w; \
    q4.x += xv4.x*mv4.x; q4.y += xv4.y*mv4.y; q4.z += xv4.z*mv4.z; q4.w += xv4.w*mv4.w; \
    q5.x += xv5.x*mv5.x; q5.y += xv5.y*mv5.y; q5.z += xv5.z*mv5.z; q5.w += xv5.w*mv5.w; \
    q6.x += xv6.x*mv6.x; q6.y += xv6.y*mv6.y; q6.z += xv6.z*mv6.z; q6.w += xv6.w*mv6.w; \
    q7.x += xv7.x*mv7.x; q7.y += xv7.y*mv7.y; q7.z += xv7.z*mv7.z; q7.w += xv7.w*mv7.w; }

// ---------------- edge scatter (b<96) || weight conv (b==96); last scatter block: row scan + dinv ----------------
__global__ void k_scatter(const int* __restrict__ ei, int* __restrict__ cell, int* __restrict__ rowlen,
                          int* __restrict__ row_ptr, float* __restrict__ dinv, int* __restrict__ dc,
                          const void* __restrict__ gW, const void* __restrict__ gB,
                          const void* __restrict__ m1W, const void* __restrict__ m1B,
                          const void* __restrict__ m2W, const void* __restrict__ m2B,
                          const void* __restrict__ m3W, const void* __restrict__ m3B,
                          const void* __restrict__ lW,  const void* __restrict__ lB,
                          const void* __restrict__ emb, int* __restrict__ modeg,
                          float* __restrict__ gwf, float* __restrict__ gbf,
                          float* __restrict__ w1f, float* __restrict__ b1f,
                          float* __restrict__ w2f, float* __restrict__ b2f,
                          float* __restrict__ w3q, float* __restrict__ linf, float* __restrict__ linb) {
    int t = threadIdx.x;
    if (blockIdx.x == 96) {
        __shared__ int bad;
        if (t == 0) bad = 0;
        __syncthreads();
        int local = 0;
        for (int i = t; i < 3232; i += 256) {
            float a = fabsf(__bfloat162float(((const bf16*)emb)[i]));
            if (!(a < 100.f)) local = 1;
        }
        if (local) atomicOr(&bad, 1);
        __syncthreads();
        int mode = bad ? 0 : 1;
        if (t == 0) *modeg = mode;
        for (int i = t; i < 2048; i += 256) {
            gwf[i] = ldf(gW, i, mode);
            w1f[i] = ldf(m1W, i, mode);
            w2f[i] = ldf(m2W, i, mode);
        }
        for (int i = t; i < 64; i += 256) { gbf[i] = ldf(gB, i, mode); linf[i] = ldf(lW, i, mode); }
        if (t < 32) { b1f[t] = ldf(m1B, t, mode); b2f[t] = ldf(m2B, t, mode); }
        // w3q row d (stride 36 floats, 16B-aligned): [W3[0..31][d], ind, b3, 0, 0]
        for (int i = t; i < 1056; i += 256) { int c = i >> 5, d = i & 31; w3q[d * 36 + c] = ldf(m3W, i, mode); }
        if (t < 32) { w3q[t * 36 + 33] = ldf(m3B, t, mode); w3q[t * 36 + 34] = 0.f; w3q[t * 36 + 35] = 0.f; }
        if (t == 0) linb[0] = ldf(lB, 0, mode);
        return;
    }
    __shared__ int amlast;
    __shared__ int sI[256];
    int e = blockIdx.x * 256 + t;
    int a = ei[e], b = ei[NE + e];
    if ((unsigned)a < (unsigned)NN && (unsigned)b < (unsigned)NN) {
        int old = atomicAdd(&cell[a * NN + b], 1);
        if (old == 0) atomicAdd(&rowlen[a], 1);
    }
    __syncthreads();
    if (t == 0) { __threadfence(); amlast = (atomicAdd(dc, 1) == 95) ? 1 : 0; }
    __syncthreads();
    if (!amlast) return;
    int i0 = 3 * t;
    int r0 = areadi(&rowlen[i0]), r1 = areadi(&rowlen[i0 + 1]), r2 = areadi(&rowlen[i0 + 2]);
    dinv[i0]     = rsqrtf((float)r0 + 1.f);
    dinv[i0 + 1] = rsqrtf((float)r1 + 1.f);
    dinv[i0 + 2] = rsqrtf((float)r2 + 1.f);
    int s3 = r0 + r1 + r2;
    sI[t] = s3;
    __syncthreads();
    for (int off = 1; off < 256; off <<= 1) {
        int tmp = (t >= off) ? sI[t - off] : 0;
        __syncthreads();
        sI[t] += tmp;
        __syncthreads();
    }
    int excl = sI[t] - s3;
    row_ptr[i0] = excl;
    row_ptr[i0 + 1] = excl + r0;
    row_ptr[i0 + 2] = excl + r0 + r1;
    if (t == 255) row_ptr[NN] = sI[255];
}

// ---------------- CSR fill + rtot (b<2304) || emb gather E -> bufA (b>=2304) ----------------
__global__ void k_fill(int* __restrict__ cell, const int* __restrict__ row_ptr, int* __restrict__ cursor,
                       int* __restrict__ col_idx, float* __restrict__ cntv, int* __restrict__ pr_row,
                       const int* __restrict__ rowlen, int* __restrict__ rtot,
                       const int* __restrict__ x, const void* __restrict__ emb,
                       const int* __restrict__ modep, float* __restrict__ bufA) {
    int t = threadIdx.x;
    int b = blockIdx.x;
    if (b < NBLK) {
        int idx = b * 256 + t;
        int i = idx / NN;
        int j = idx - i * NN;
        int cv = cell[idx];
        if (cv > 0) {
            int p = row_ptr[i] + atomicAdd(&cursor[i], 1);
            col_idx[p] = j; cntv[p] = (float)cv; pr_row[p] = i;
            cell[idx] = p;
            atomicAdd(&rtot[i], rowlen[j]);
        } else cell[idx] = -1;
    } else {
        int idx = (b - NBLK) * 256 + t;   // 768*32
        int i = idx >> 5, k = idx & 31;
        int xi = x[i]; if (xi < 0) xi = 0; if (xi > 100) xi = 100;
        bufA[idx] = ldf(emb, xi * 32 + k, *modep);
    }
}

// ---------------- b==0: row_base scan || b>=1: agg(E) then @W0 -> bufB ----------------
__global__ void k_aggmw0(const int* __restrict__ rtot, int* __restrict__ row_base,
                         const int* __restrict__ row_ptr, const int* __restrict__ col_idx,
                         const float* __restrict__ bufA, const float* __restrict__ dinv,
                         const float* __restrict__ gwf, const float* __restrict__ gbf,
                         float* __restrict__ bufB) {
    int t = threadIdx.x;
    if (blockIdx.x == 0) {
        __shared__ int sI[256];
        int r3[3]; int s3 = 0;
#pragma unroll
        for (int q = 0; q < 3; q++) { r3[q] = rtot[3 * t + q]; s3 += r3[q]; }
        sI[t] = s3;
        __syncthreads();
        for (int off = 1; off < 256; off <<= 1) {
            int tmp = (t >= off) ? sI[t - off] : 0;
            __syncthreads();
            sI[t] += tmp;
            __syncthreads();
        }
        int run = sI[t] - s3;
        row_base[3 * t] = run;
        row_base[3 * t + 1] = run + r3[0];
        row_base[3 * t + 2] = run + r3[0] + r3[1];
        return;
    }
    __shared__ float sg[8][32];
    int li = t >> 5, k = t & 31;
    int i = (blockIdx.x - 1) * 8 + li;
    int base = row_ptr[i], len = row_ptr[i + 1] - base;
    float di = dinv[i];
    float acc = di * bufA[i * 32 + k];
    for (int e = 0; e < len; e++) {
        int c = col_idx[base + e];
        acc += dinv[c] * bufA[c * 32 + k];
    }
    sg[li][k] = di * acc;
    __syncthreads();
    int d = k;
    float s = gbf[d];
#pragma unroll
    for (int kk = 0; kk < 32; kk++) s += sg[li][kk] * gwf[kk * 32 + d];
    bufB[i * 32 + d] = s;
}

// ---------------- per-row path histogram (b<768) || nrm0 from bufB (b==768) ----------------
__global__ void k_hist(const int* __restrict__ row_ptr, const int* __restrict__ col_idx,
                       const int* __restrict__ row_base,
                       int* __restrict__ pcur, int2* __restrict__ paths2, int cap,
                       const float* __restrict__ bufB, float* __restrict__ nrm0) {
    int t = threadIdx.x;
    if (blockIdx.x == NN) {
        __shared__ float r1[256], r2[256];
        int dd = t & 31, g = t >> 5;
        float s = 0.f, s2 = 0.f;
        for (int r = g; r < NN; r += 8) { float v = bufB[r * 32 + dd]; s += v; s2 += v * v; }
        r1[t] = s; r2[t] = s2;
        __syncthreads();
        if (t < 32) {
            float a = 0.f, b2 = 0.f;
            for (int k = 0; k < 8; k++) { a += r1[k * 32 + t]; b2 += r2[k * 32 + t]; }
            float mean = a / (float)NN;
            float var = b2 / (float)NN - mean * mean;
            nrm0[t] = mean;
            nrm0[32 + t] = rsqrtf(fmaxf(var, 0.f) + 1e-5f);
        }
        return;
    }
    __shared__ int hist[NN];
    __shared__ int sc[256];
    int i = blockIdx.x;
    int base = row_ptr[i], len = row_ptr[i + 1] - base;
    int rb = row_base[i];
    int wave = t >> 6, lane = t & 63;
    for (int j = t; j < NN; j += 256) hist[j] = 0;
    __syncthreads();
    for (int ee = wave; ee < len; ee += 4) {
        int k = col_idx[base + ee];
        int kb = row_ptr[k], ke = row_ptr[k + 1];
        for (int e = kb + lane; e < ke; e += 64) atomicAdd(&hist[col_idx[e]], 1);
    }
    __syncthreads();
    int h0 = hist[3 * t], h1 = hist[3 * t + 1], h2 = hist[3 * t + 2];
    int s3 = h0 + h1 + h2;
    sc[t] = s3;
    __syncthreads();
    for (int off = 1; off < 256; off <<= 1) {
        int tmp = (t >= off) ? sc[t - off] : 0;
        __syncthreads();
        sc[t] += tmp;
        __syncthreads();
    }
    int excl = sc[t] - s3;
    int n0 = i * NN + 3 * t;
    pcur[n0]     = rb + excl + h0;            // absolute END offsets
    pcur[n0 + 1] = rb + excl + h0 + h1;
    pcur[n0 + 2] = rb + excl + h0 + h1 + h2;
    hist[3 * t] = excl;
    hist[3 * t + 1] = excl + h0;
    hist[3 * t + 2] = excl + h0 + h1;
    __syncthreads();
    for (int ee = wave; ee < len; ee += 4) {
        int e1 = base + ee;
        int k = col_idx[e1];
        int kb = row_ptr[k], ke = row_ptr[k + 1];
        for (int e = kb + lane; e < ke; e += 64) {
            int j = col_idx[e];
            int slot = rb + atomicAdd(&hist[j], 1);
            if (slot < cap) paths2[slot] = make_int2(e1, e);
        }
    }
}

// ---------------- agg(g(bufB,nrm0)) then @W1 -> bufA ; accumulate stats1 partials ----------------
__global__ void k_aggmw1(const int* __restrict__ row_ptr, const int* __restrict__ col_idx,
                         const float* __restrict__ bufB, const float* __restrict__ nrm0,
                         const float* __restrict__ dinv,
                         const float* __restrict__ gwf, const float* __restrict__ gbf,
                         float* __restrict__ bufA, float* __restrict__ stats1) {
    __shared__ float sg[8][32];
    int t = threadIdx.x;
    int li = t >> 5, k = t & 31;
    int i = blockIdx.x * 8 + li;
    float mk = nrm0[k], rk = nrm0[32 + k];
    int base = row_ptr[i], len = row_ptr[i + 1] - base;
    float di = dinv[i];
    float acc = di * fmaxf((bufB[i * 32 + k] - mk) * rk, 0.f);
    for (int e = 0; e < len; e++) {
        int c = col_idx[base + e];
        acc += dinv[c] * fmaxf((bufB[c * 32 + k] - mk) * rk, 0.f);
    }
    sg[li][k] = di * acc;
    __syncthreads();
    int d = k;
    const float* W = gwf + 1024;
    float s = gbf[32 + d];
#pragma unroll
    for (int kk = 0; kk < 32; kk++) s += sg[li][kk] * W[kk * 32 + d];
    bufA[i * 32 + d] = s;
    __syncthreads();
    sg[li][d] = s;   // reuse LDS for column partials
    __syncthreads();
    if (t < 32) {
        float ps = 0.f, ps2 = 0.f;
#pragma unroll
        for (int q = 0; q < 8; q++) { float v = sg[q][t]; ps += v; ps2 += v * v; }
        float* rep = stats1 + (blockIdx.x & (NREP - 1)) * 80;
        atomicAdd(&rep[t], ps);
        atomicAdd(&rep[32 + t], ps2);
    }
}

// ---------------- edge MLP (b<3072) || h write (b>=3072); nrm1 computed locally ----------------
__global__ void k_emlp(const float* __restrict__ bufA, const float* __restrict__ stats1,
                       const int* __restrict__ row_ptr, const int* __restrict__ col_idx,
                       const int* __restrict__ pr_row, const float* __restrict__ cntv,
                       const float* __restrict__ w1f, const float* __restrict__ b1f,
                       const float* __restrict__ w2f, const float* __restrict__ b2f,
                       float* __restrict__ xep, float* __restrict__ mulp, float* __restrict__ h) {
    __shared__ float nmean[32], nrstd[32];
    int t = threadIdx.x;
    int b = blockIdx.x;
    if (t < 32) {
        float s = 0.f, s2 = 0.f;
#pragma unroll
        for (int r = 0; r < NREP; r++) { s += stats1[r * 80 + t]; s2 += stats1[r * 80 + 32 + t]; }
        float mean = s / (float)NN;
        float var = s2 / (float)NN - mean * mean;
        nmean[t] = mean;
        nrstd[t] = rsqrtf(fmaxf(var, 0.f) + 1e-5f);
    }
    __syncthreads();
    if (b < 3072) {
        int d = t & 31;
        int p = b * 8 + (t >> 5);
        if (p >= row_ptr[NN]) {
            if (p < NE) { xep[p * 32 + d] = 0.f; mulp[p * 32 + d] = 0.f; }
            return;
        }
        int i = pr_row[p], j = col_idx[p];
        float a1 = b1f[d], a2 = b2f[d];
#pragma unroll
        for (int c = 0; c < 32; c++) {
            float hv = fmaxf((bufA[i * 32 + c] - nmean[c]) * nrstd[c], 0.f);
            a1 += hv * w1f[c * 32 + d];
            a2 += hv * w2f[c * 32 + d];
        }
#pragma unroll
        for (int c = 0; c < 32; c++) {
            float hv = fmaxf((bufA[j * 32 + c] - nmean[c]) * nrstd[c], 0.f);
            a1 += hv * w1f[(32 + c) * 32 + d];
            a2 += hv * w2f[(32 + c) * 32 + d];
        }
        float cv = cntv[p];
        xep[p * 32 + d]  = cv * fmaxf(a1, 0.f);
        mulp[p * 32 + d] = cv * fmaxf(a2, 0.f);
    } else {
        int idx = (b - 3072) * 256 + t;
        int d = idx & 31;
        h[idx] = fmaxf((bufA[idx] - nmean[d]) * nrstd[d], 0.f);
    }
}

// ---------------- fused big: 256 thr, 2 cells/thread, big VGPR budget for load pipelining ----------------
__global__ __launch_bounds__(256, 2) void k_big(const int* __restrict__ pcur,
                                                const int2* __restrict__ paths2,
                                                const int* __restrict__ cell,
                                                const float4* __restrict__ xep4, const float4* __restrict__ mulp4,
                                                const float* __restrict__ w3q,
                                                float* __restrict__ stats, int* __restrict__ done,
                                                float* __restrict__ nrm, int cap) {
    __shared__ float sS1[32], sS2[32];
    __shared__ float sCm;
    __shared__ int amlast;
    int t = threadIdx.x, lane = t & 63;
    int b = blockIdx.x;
    int n0 = b * 512 + 2 * t;
    if (t == 0) sCm = 0.f;
    if (t < 32) { sS1[t] = 0.f; sS2[t] = 0.f; }
    __syncthreads();
    int p0a = (n0 == 0) ? 0 : pcur[n0 - 1];
    int p1a = pcur[n0];
    int p1b = pcur[n0 + 1];
    if (p0a > cap) p0a = cap; if (p1a > cap) p1a = cap; if (p1b > cap) p1b = cap;
    int lenA = p1a - p0a, lenB = p1b - p1a;
    int lim = (lenA > lenB) ? lenA : lenB;
    float4 a0 = {0.f,0.f,0.f,0.f}, a1 = a0, a2 = a0, a3 = a0, a4 = a0, a5 = a0, a6 = a0, a7 = a0;
    float4 c0 = a0, c1 = a0, c2 = a0, c3 = a0, c4 = a0, c5 = a0, c6 = a0, c7 = a0;
    for (int q = 0; q < lim; q++) {
        int2 recA, recB;
        bool doA = q < lenA, doB = q < lenB;
        if (doA) recA = paths2[p0a + q];
        if (doB) recB = paths2[p1a + q];
        if (doA) GATH(recA, a0, a1, a2, a3, a4, a5, a6, a7);
        if (doB) GATH(recB, c0, c1, c2, c3, c4, c5, c6, c7);
    }
    bool adja = cell[n0] >= 0;
    bool adjb = cell[n0 + 1] >= 0;
    float afa = adja ? 1.f : 0.f;
    float afb = adjb ? 1.f : 0.f;
    float mska = (lenA > 0 || adja) ? 1.f : 0.f;
    float mskb = (lenB > 0 || adjb) ? 1.f : 0.f;
#pragma unroll
    for (int ch = 0; ch < 2; ch++) {
        float v[32];
#pragma unroll
        for (int j = 0; j < 16; j++) {
            int dd = ch * 16 + j;
            const float4* wr = (const float4*)(w3q + dd * 36);   // wave-uniform -> s_load, shared by both cells
            float4 wv = wr[8];
            float za = wv.y + afa * wv.x;
            float zb = wv.y + afb * wv.x;
            wv = wr[0]; DOT4(za, a0, wv); DOT4(zb, c0, wv);
            wv = wr[1]; DOT4(za, a1, wv); DOT4(zb, c1, wv);
            wv = wr[2]; DOT4(za, a2, wv); DOT4(zb, c2, wv);
            wv = wr[3]; DOT4(za, a3, wv); DOT4(zb, c3, wv);
            wv = wr[4]; DOT4(za, a4, wv); DOT4(zb, c4, wv);
            wv = wr[5]; DOT4(za, a5, wv); DOT4(zb, c5, wv);
            wv = wr[6]; DOT4(za, a6, wv); DOT4(zb, c6, wv);
            wv = wr[7]; DOT4(za, a7, wv); DOT4(zb, c7, wv);
            v[j] = mska * za + mskb * zb;
            v[16 + j] = mska * za * za + mskb * zb * zb;
        }
#pragma unroll
        for (int i2 = 0; i2 < 32; i2++) v[i2] += __shfl_xor(v[i2], 32);
        redRound<16, 16>(v, lane);
        redRound<8, 8>(v, lane);
        redRound<4, 4>(v, lane);
        redRound<2, 2>(v, lane);
        redRound<1, 1>(v, lane);
        if (lane < 32) {
            if (lane < 16) atomicAdd(&sS1[ch * 16 + lane], v[0]);
            else           atomicAdd(&sS2[ch * 16 + lane - 16], v[0]);
        }
    }
    {
        float cm2 = mska + mskb;
        for (int off = 32; off >= 1; off >>= 1) cm2 += __shfl_xor(cm2, off);
        if (lane == 0) atomicAdd(&sCm, cm2);
    }
    __syncthreads();
    float* srep = stats + (b & (NREP - 1)) * 80;
    if (t < 32) {
        atomicAdd(&srep[t], sS1[t]);
        atomicAdd(&srep[32 + t], sS2[t]);
    }
    if (t == 32) atomicAdd(&srep[64], sCm);
    __syncthreads();
    if (t == 0) {
        __threadfence();
        amlast = (atomicAdd(done, 1) == NBLK2 - 1) ? 1 : 0;
    }
    __syncthreads();
    if (amlast && t < 32) {
        float sum1 = 0.f, sum2 = 0.f;
        for (int r = 0; r < NREP; r++) {
            sum1 += aread(&stats[r * 80 + t]);
            sum2 += aread(&stats[r * 80 + 32 + t]);
        }
        float cmv = 0.f;
        for (int r = 0; r < NREP; r++) cmv += aread(&stats[r * 80 + 64]);
        if (cmv < 1.f) cmv = 1.f;
        float mean = sum1 / cmv;
        float var = sum2 / cmv - mean * mean;
        nrm[t] = mean;
        nrm[32 + t] = rsqrtf(fmaxf(var, 0.f) + 1e-5f);
    }
}

// ---------------- output: C at pos pairs via path lists, norm, sym, linear ----------------
__global__ void k_out(const int* __restrict__ pos, const int* __restrict__ pcur,
                      const int2* __restrict__ paths2,
                      const int* __restrict__ cell,
                      const float* __restrict__ xep, const float* __restrict__ mulp,
                      const float* __restrict__ h,
                      const float* __restrict__ w3q,
                      const float* __restrict__ nrm,
                      const float* __restrict__ linf, const float* __restrict__ linb,
                      const int* __restrict__ modep, int cap, void* __restrict__ outp) {
    __shared__ float Cb[4][2][32];
    int t = threadIdx.x;
    int w = t >> 6, lane = t & 63, d = lane & 31, dir = lane >> 5;
    int p = blockIdx.x * 4 + w;
    int a = pos[2 * p], b = pos[2 * p + 1];
    if ((unsigned)a >= (unsigned)NN) a = 0;
    if ((unsigned)b >= (unsigned)NN) b = 0;
    int r = dir ? b : a;
    int cc = dir ? a : b;
    int n = r * NN + cc;
    int p1 = pcur[n];
    int p0 = (n == 0) ? 0 : pcur[n - 1];
    if (p0 > cap) p0 = cap; if (p1 > cap) p1 = cap;
    float acc = 0.f;
    for (int q = p0; q < p1; q++) {
        int2 rec = paths2[q];
        acc += xep[rec.x * 32 + d] * mulp[rec.y * 32 + d];
    }
    Cb[w][dir][d] = acc;
    bool adj = cell[n] >= 0;
    float msk = (p1 > p0 || adj) ? 1.f : 0.f;
    __syncthreads();
    float z = w3q[d * 36 + 33] + (adj ? 1.f : 0.f) * w3q[d * 36 + 32];
#pragma unroll
    for (int c = 0; c < 32; c++) z += Cb[w][dir][c] * w3q[d * 36 + c];
    float zn = fmaxf((z - nrm[d]) * nrm[32 + d], 0.f);
    float zp = __shfl_xor(zn, 32);
    float symd = msk * zn * zp;
    float xxd = h[a * 32 + d] * h[b * 32 + d];
    float contrib = symd * linf[d] + xxd * linf[32 + d];
    for (int off = 16; off >= 1; off >>= 1) contrib += __shfl_xor(contrib, off);
    if (lane == 0) {
        float v = contrib + linb[0];
        v = fminf(fmaxf(v, -1e4f), 1e4f);
        if (*modep) ((bf16*)outp)[p] = __float2bfloat16(v);
        else        ((float*)outp)[p] = v;
    }
}

extern "C" void kernel_launch(void* const* d_in, const int* in_sizes, int n_in,
                              void* d_out, int out_size, void* d_ws, size_t ws_size,
                              hipStream_t stream) {
    const void* px  = d_in[0];  const void* pei = d_in[1];  const void* ppos = d_in[2];
    const void* pemb = d_in[3]; const void* pgW = d_in[4];  const void* pgB  = d_in[5];
    const void* pm1W = d_in[6]; const void* pm1B = d_in[7]; const void* pm2W = d_in[8];
    const void* pm2B = d_in[9]; const void* pm3W = d_in[10]; const void* pm3B = d_in[11];
    const void* plW = d_in[12]; const void* plB = d_in[13];
    {
        int c2048 = 0, c64 = 0, c32 = 0;
        for (int i = 0; i < n_in; i++) {
            int s = in_sizes[i]; const void* p = d_in[i];
            switch (s) {
                case 768:   px = p; break;
                case 49152: pei = p; break;
                case 8192:  ppos = p; break;
                case 3232:  pemb = p; break;
                case 2048:  if (c2048 == 0) pgW = p; else if (c2048 == 1) pm1W = p; else pm2W = p; c2048++; break;
                case 64:    if (c64 == 0) pgB = p; else plW = p; c64++; break;
                case 32:    if (c32 == 0) pm1B = p; else if (c32 == 1) pm2B = p; else pm3B = p; c32++; break;
                case 1056:  pm3W = p; break;
                case 1:     plB = p; break;
                default: break;
            }
        }
    }

    char* ws = (char*)d_ws;
    size_t off = 0;
    auto alloc = [&](size_t bytes) -> void* {
        void* pp = ws + off;
        off += (bytes + 255) & ~(size_t)255;
        return pp;
    };
    int*   cell    = (int*)alloc(NCELL * 4);
    int*   pcur    = (int*)alloc(NCELL * 4);
    // ---- contiguous aux region (zeroed by one memset) ----
    char*  aux0    = ws + off;
    int*   rowlen  = (int*)alloc(NN * 4);
    int*   rtot    = (int*)alloc(NN * 4);
    int*   cursor  = (int*)alloc(NN * 4);
    float* stats   = (float*)alloc(NREP * 80 * 4);
    float* stats1  = (float*)alloc(NREP * 80 * 4);
    int*   dcs     = (int*)alloc(8 * 4);
    size_t auxlen  = (ws + off) - aux0;
    // ------------------------------------------------------
    int*   row_base= (int*)alloc(NN * 4);
    int*   row_ptr = (int*)alloc((NN + 1) * 4);
    int*   col_idx = (int*)alloc(NE * 4);
    float* cntv    = (float*)alloc(NE * 4);
    int*   pr_row  = (int*)alloc(NE * 4);
    float* dinv    = (float*)alloc(NN * 4);
    float* h       = (float*)alloc(NN * 32 * 4);
    float* bufA    = (float*)alloc(NN * 32 * 4);
    float* bufB    = (float*)alloc(NN * 32 * 4);
    float* xep     = (float*)alloc(NE * 32 * 4);
    float* mulp    = (float*)alloc(NE * 32 * 4);
    float* nrm     = (float*)alloc(64 * 4);
    float* nrm0    = (float*)alloc(64 * 4);
    float* gwf     = (float*)alloc(2048 * 4);
    float* gbf     = (float*)alloc(64 * 4);
    float* w1f     = (float*)alloc(2048 * 4);
    float* b1f     = (float*)alloc(32 * 4);
    float* w2f     = (float*)alloc(2048 * 4);
    float* b2f     = (float*)alloc(32 * 4);
    float* w3q     = (float*)alloc(32 * 36 * 4);
    float* linf    = (float*)alloc(64 * 4);
    float* linb    = (float*)alloc(4);
    int*   modeg   = (int*)alloc(4);
    size_t remain = (ws_size > off) ? (ws_size - off) : 0;
    int cap = (int)(remain / 8);
    if (cap > (1 << 20)) cap = (1 << 20);
    int2*  paths2  = (int2*)alloc((size_t)cap * 8);

    hipMemsetAsync(cell, 0, (size_t)NCELL * 4, stream);
    hipMemsetAsync(aux0, 0, auxlen, stream);
    k_scatter<<<97, 256, 0, stream>>>((const int*)pei, cell, rowlen, row_ptr, dinv, &dcs[0],
                                      pgW, pgB, pm1W, pm1B, pm2W, pm2B, pm3W, pm3B, plW, plB,
                                      pemb, modeg, gwf, gbf, w1f, b1f, w2f, b2f, w3q, linf, linb);
    k_fill<<<NBLK + 96, 256, 0, stream>>>(cell, row_ptr, cursor, col_idx, cntv, pr_row,
                                          rowlen, rtot, (const int*)px, pemb, modeg, bufA);
    k_aggmw0<<<1 + 96, 256, 0, stream>>>(rtot, row_base, row_ptr, col_idx, bufA, dinv, gwf, gbf, bufB);
    k_hist<<<NN + 1, 256, 0, stream>>>(row_ptr, col_idx, row_base, pcur, paths2, cap, bufB, nrm0);
    k_aggmw1<<<96, 256, 0, stream>>>(row_ptr, col_idx, bufB, nrm0, dinv, gwf, gbf, bufA, stats1);
    k_emlp<<<3072 + 96, 256, 0, stream>>>(bufA, stats1, row_ptr, col_idx, pr_row, cntv,
                                          w1f, b1f, w2f, b2f, xep, mulp, h);
    k_big<<<NBLK2, 256, 0, stream>>>(pcur, paths2, cell, (const float4*)xep, (const float4*)mulp,
                                     w3q, stats, &dcs[1], nrm, cap);
    k_out<<<NPOS / 4, 256, 0, stream>>>((const int*)ppos, pcur, paths2, cell, xep, mulp, h,
                                        w3q, nrm, linf, linb, modeg, cap, d_out);
}